// Round 1
// 424.936 us; speedup vs baseline: 1.0358x; 1.0358x over previous
//
#include <hip/hip_runtime.h>
#include <stdint.h>
#include <math.h>

// Problem constants (reference file)
#define NROW 8192   // N rows of input
#define KDIM 2048   // F_IN
#define NDIM 2048   // F_OUT
//
// Reference reduces EXACTLY to out = elu(input @ W):
//   scores = where(eye>0, e, -9e15) -> softmax rows one-hot (exp(-9e15)==0 in fp32)
//   attention = I -> h_prime = h.  adj and a are numerically unused.

typedef __attribute__((ext_vector_type(8)))  short bf16x8;   // 8 bf16 = 4 VGPRs
typedef __attribute__((ext_vector_type(16))) float f32x16;   // 32x32 MFMA acc

__device__ __forceinline__ unsigned short f32_to_bf16(float f) {
    union { float f; unsigned int u; } v; v.f = f;
    unsigned int u = v.u;
    unsigned int r = u + 0x7FFFu + ((u >> 16) & 1u);  // RNE
    return (unsigned short)(r >> 16);
}

// Fused prep: blocks [0, 16384) convert input fp32->bf16 (vectorized);
// blocks [16384, 20480) transpose+convert W (KxN fp32) -> Wt (NxK bf16).
#define CVT_BLOCKS (NROW * KDIM / 4 / 256)          // 16384
#define TRN_BLOCKS ((NDIM / 32) * (KDIM / 32))      // 4096

__global__ void prep_kernel(const float* __restrict__ in,
                            unsigned short* __restrict__ Abf,
                            const float* __restrict__ W,
                            unsigned short* __restrict__ Wt) {
    __shared__ float tile[32][33];  // +1 pad: conflict-free transpose
    int tid = threadIdx.x;
    if (blockIdx.x < CVT_BLOCKS) {
        int i = (blockIdx.x * 256 + tid) * 4;
        float4 f = *(const float4*)(in + i);
        ushort4 o;
        o.x = f32_to_bf16(f.x);
        o.y = f32_to_bf16(f.y);
        o.z = f32_to_bf16(f.z);
        o.w = f32_to_bf16(f.w);
        *(ushort4*)(Abf + i) = o;
    } else {
        int b = blockIdx.x - CVT_BLOCKS;
        int x0 = (b & 63) * 32;        // N coord
        int y0 = (b >> 6) * 32;        // K coord
        int tx = tid & 31, ty = tid >> 5;   // (32, 8)
        #pragma unroll
        for (int j = 0; j < 32; j += 8)
            tile[ty + j][tx] = W[(size_t)(y0 + ty + j) * NDIM + x0 + tx];
        __syncthreads();
        #pragma unroll
        for (int j = 0; j < 32; j += 8)
            Wt[(size_t)(x0 + ty + j) * KDIM + y0 + tx] = f32_to_bf16(tile[tx][ty + j]);
    }
}

// ---------------- GEMM: C[M,N] = elu(A[M,K] * Wt[N,K]^T) ----------------
// 256x256 tile, BK=64, 8 waves (2M x 4N), per-wave C = 128x64, 32x32x16 MFMA.
// 8-phase-style schedule (T3+T4+T5 from the catalog):
//   - LDS = 5-slot ring of 16 KB half-tiles per operand (160 KB total, 1 blk/CU)
//   - phase = one k-slice: 6x ds_read_b128 + 1 half-tile prefetch + 8 MFMA
//   - raw s_barrier (NOT __syncthreads: that drains vmcnt(0) and kills the pipe)
//   - counted s_waitcnt vmcnt(4) once per K-tile: 2 half-tile loads stay in
//     flight across barriers (ledger: chunk j issued at phase j-6; at tile-T
//     boundary issued<=4T+9, need<=4T+7 done -> 2 chunks * 2 loads = vmcnt(4))
//   - s_setprio(1) around the MFMA cluster
// XOR source-chunk swizzle retained from previous version: LDS (row, slot)
// holds global chunk (row, slot ^ (row&7)); reads XOR the same way ->
// conflict-free ds_read_b128 at 128 B row stride.
#define BM 256
#define BN 256
#define BK 64
#define NT (KDIM / BK)          // 32 K-tiles
#define SLOT_SH (128 * 64)      // shorts per half-tile slot (16 KB)

__device__ __forceinline__ void async_ld16(const unsigned short* g, unsigned short* l) {
    __builtin_amdgcn_global_load_lds(
        (const __attribute__((address_space(1))) void*)g,
        (__attribute__((address_space(3))) void*)l,
        16, 0, 0);
}

__global__ __launch_bounds__(512, 2)
void gemm_8phase(const unsigned short* __restrict__ A,   // M x K bf16
                 const unsigned short* __restrict__ Bt,  // N x K bf16 (= W^T)
                 float* __restrict__ C) {                // M x N fp32
    __shared__ unsigned short lds[10 * SLOT_SH];   // 160 KB exactly (5 A + 5 B)
    unsigned short* const Abase = lds;
    unsigned short* const Bbase = lds + 5 * SLOT_SH;

    const int tid  = threadIdx.x;
    const int wave = tid >> 6;
    const int lane = tid & 63;
    const int l32  = lane & 31;
    const int kh8  = (lane >> 5) << 3;   // k sub-offset within 16-slice (shorts)
    const int rx8  = (l32 & 7) << 3;     // row&7 XOR term (shorts)
    const int wr   = wave >> 2;          // 0/1: M half of block tile
    const int wc   = wave & 3;           // 0..3: N quarter of block tile
    const int hB   = wc >> 1;            // which B half-tile this wave reads
    const int brow = (wc & 1) * 64;      // row base within B half-tile

    // XCD-aware swizzle: 256 blocks, 8 XCDs, 32 contiguous blocks per XCD
    // (nwg % 8 == 0 -> simple form is bijective).
    const int bid = blockIdx.x;
    const int swz = (bid & 7) * 32 + (bid >> 3);
    const int m0 = (swz >> 3) * BM;      // 32 M-blocks
    const int n0 = (swz & 7) * BN;       // 8  N-blocks

    // Staging: half-tile = 128 rows x 64 k bf16 = 1024 16B-chunks; 512 threads
    // x 2 loads. Thread covers chunks {tid, tid+512} -> rows r0, r0+64.
    // Global k pre-swizzled so linear global_load_lds dest = swizzled layout.
    const int r0 = tid >> 3, s0 = tid & 7;
    const int xo = (s0 ^ (r0 & 7)) << 3;
    const unsigned short* const gA = A  + (size_t)(m0 + r0) * KDIM + xo;
    const unsigned short* const gB = Bt + (size_t)(n0 + r0) * KDIM + xo;

    // chunk j: tile t=j>>2, cc=j&3: 0=A-h0, 1=B-h0, 2=A-h1, 3=B-h1.
    // Ring slot for (t, h) = (2t+h) % 5 (per operand).
    auto stage = [&](int j) {
        const int t   = j >> 2;
        const int isB = j & 1;
        const int h   = (j >> 1) & 1;
        const int slot = (2 * t + h) % 5;
        const unsigned short* g = (isB ? gB : gA)
            + (size_t)h * 128 * KDIM + (size_t)t * BK;
        unsigned short* l = (isB ? Bbase : Abase) + slot * SLOT_SH + tid * 8;
        async_ld16(g, l);
        async_ld16(g + (size_t)64 * KDIM, l + 512 * 8);
    };

    f32x16 acc[4][2];
    #pragma unroll
    for (int i = 0; i < 4; ++i)
        #pragma unroll
        for (int j2 = 0; j2 < 2; ++j2) {
            f32x16 z = {0.f,0.f,0.f,0.f,0.f,0.f,0.f,0.f,
                        0.f,0.f,0.f,0.f,0.f,0.f,0.f,0.f};
            acc[i][j2] = z;
        }

    // Prologue: tile0 (chunks 0-3) + tile1 first half (chunks 4,5).
    // vmcnt(4): tile0's 8 loads done; chunks 4,5 may stay in flight.
    #pragma unroll
    for (int j = 0; j < 6; ++j) stage(j);
    asm volatile("s_waitcnt vmcnt(4)" ::: "memory");
    asm volatile("s_barrier" ::: "memory");

    for (int T = 0; T < NT; ++T) {
        const int slotA = (2 * T + wr) % 5;
        const int slotB = (2 * T + hB) % 5;
        const unsigned short* const As_ = Abase + slotA * SLOT_SH;
        const unsigned short* const Bs_ = Bbase + slotB * SLOT_SH;
        #pragma unroll
        for (int ks = 0; ks < 4; ++ks) {   // 4 phases per K-tile
            const int kc = (ks * 16 + kh8) ^ rx8;
            bf16x8 af[4], bf[2];
            #pragma unroll
            for (int i = 0; i < 4; ++i)
                af[i] = *(const bf16x8*)(As_ + (i * 32 + l32) * 64 + kc);
            #pragma unroll
            for (int j2 = 0; j2 < 2; ++j2)
                bf[j2] = *(const bf16x8*)(Bs_ + (brow + j2 * 32 + l32) * 64 + kc);

            const int j = 4 * T + ks + 6;   // prefetch 1.5 tiles ahead
            if (j < 4 * NT) stage(j);

            __builtin_amdgcn_s_barrier();
            __builtin_amdgcn_s_setprio(1);
            #pragma unroll
            for (int i = 0; i < 4; ++i)
                #pragma unroll
                for (int j2 = 0; j2 < 2; ++j2)
                    acc[i][j2] = __builtin_amdgcn_mfma_f32_32x32x16_bf16(
                        af[i], bf[j2], acc[i][j2], 0, 0, 0);
            __builtin_amdgcn_s_setprio(0);

            // Pin this phase's ds_reads complete before the barrier (slot is
            // recycled 2.5 tiles later; MFMA could otherwise sink past b2).
            asm volatile("s_waitcnt lgkmcnt(0)" ::: "memory");
            if (ks == 3) {
                if (T < NT - 2)       asm volatile("s_waitcnt vmcnt(4)" ::: "memory");
                else if (T == NT - 2) asm volatile("s_waitcnt vmcnt(0)" ::: "memory");
                // T == NT-1: nothing left in flight, no wait needed
            }
            asm volatile("s_barrier" ::: "memory");
        }
    }

    // Epilogue: C/D layout (m74/m101): col=lane&31, row=(r&3)+8*(r>>2)+4*(lane>>5)
    const int kh = kh8 >> 3;
    #pragma unroll
    for (int i = 0; i < 4; ++i)
        #pragma unroll
        for (int j2 = 0; j2 < 2; ++j2)
            #pragma unroll
            for (int r = 0; r < 16; ++r) {
                int row = (r & 3) + 8 * (r >> 2) + 4 * kh;
                int m = m0 + wr * 128 + i * 32 + row;
                int col = n0 + wc * 64 + j2 * 32 + l32;
                float v = acc[i][j2][r];
                C[(size_t)m * NDIM + col] = (v > 0.f) ? v : (__expf(v) - 1.f);
            }
}

extern "C" void kernel_launch(void* const* d_in, const int* in_sizes, int n_in,
                              void* d_out, int out_size, void* d_ws, size_t ws_size,
                              hipStream_t stream) {
    const float* input = (const float*)d_in[0];
    // d_in[1] = adj : numerically unused (attention == I exactly)
    const float* W     = (const float*)d_in[2];
    // d_in[3] = a   : numerically unused
    float* out = (float*)d_out;

    // Workspace: A_bf16 (33.5 MB) then Wt_bf16 (8.4 MB)
    unsigned short* Abf = (unsigned short*)d_ws;
    unsigned short* Wt  = Abf + (size_t)NROW * KDIM;

    prep_kernel<<<CVT_BLOCKS + TRN_BLOCKS, 256, 0, stream>>>(input, Abf, W, Wt);
    gemm_8phase<<<dim3((NROW / BM) * (NDIM / BN)), 512, 0, stream>>>(Abf, Wt, out);
}

// Round 2
// 420.156 us; speedup vs baseline: 1.0476x; 1.0114x over previous
//
#include <hip/hip_runtime.h>
#include <stdint.h>
#include <math.h>

// Problem constants (reference file)
#define NROW 8192   // N rows of input
#define KDIM 2048   // F_IN
#define NDIM 2048   // F_OUT
//
// Reference reduces EXACTLY to out = elu(input @ W):
//   scores = where(eye>0, e, -9e15) -> softmax rows one-hot (exp(-9e15)==0 in fp32)
//   attention = I -> h_prime = h.  adj and a are numerically unused.

typedef __attribute__((ext_vector_type(8)))  short bf16x8;   // 8 bf16 = 4 VGPRs
typedef __attribute__((ext_vector_type(16))) float f32x16;   // 32x32 MFMA acc

__device__ __forceinline__ unsigned short f32_to_bf16(float f) {
    union { float f; unsigned int u; } v; v.f = f;
    unsigned int u = v.u;
    unsigned int r = u + 0x7FFFu + ((u >> 16) & 1u);  // RNE
    return (unsigned short)(r >> 16);
}

// Fused prep: blocks [0, 16384) convert input fp32->bf16 (vectorized);
// blocks [16384, 20480) transpose+convert W (KxN fp32) -> Wt (NxK bf16).
#define CVT_BLOCKS (NROW * KDIM / 4 / 256)          // 16384
#define TRN_BLOCKS ((NDIM / 32) * (KDIM / 32))      // 4096

__global__ void prep_kernel(const float* __restrict__ in,
                            unsigned short* __restrict__ Abf,
                            const float* __restrict__ W,
                            unsigned short* __restrict__ Wt) {
    __shared__ float tile[32][33];  // +1 pad: conflict-free transpose
    int tid = threadIdx.x;
    if (blockIdx.x < CVT_BLOCKS) {
        int i = (blockIdx.x * 256 + tid) * 4;
        float4 f = *(const float4*)(in + i);
        ushort4 o;
        o.x = f32_to_bf16(f.x);
        o.y = f32_to_bf16(f.y);
        o.z = f32_to_bf16(f.z);
        o.w = f32_to_bf16(f.w);
        *(ushort4*)(Abf + i) = o;
    } else {
        int b = blockIdx.x - CVT_BLOCKS;
        int x0 = (b & 63) * 32;        // N coord
        int y0 = (b >> 6) * 32;        // K coord
        int tx = tid & 31, ty = tid >> 5;   // (32, 8)
        #pragma unroll
        for (int j = 0; j < 32; j += 8)
            tile[ty + j][tx] = W[(size_t)(y0 + ty + j) * NDIM + x0 + tx];
        __syncthreads();
        #pragma unroll
        for (int j = 0; j < 32; j += 8)
            Wt[(size_t)(x0 + ty + j) * KDIM + y0 + tx] = f32_to_bf16(tile[tx][ty + j]);
    }
}

// ---------------- GEMM: C[M,N] = elu(A[M,K] * Wt[N,K]^T) ----------------
// 256x256 tile, BK=64, 8 waves (2M x 4N), per-wave C = 128x64, 32x32x16 MFMA.
// AITER-style single-barrier-per-K-tile pipeline (s02 schedule):
//   - LDS = 5-slot ring of 16 KB half-tiles per operand (160 KB, 1 blk/CU)
//   - per K-tile: ONE s_barrier (32 total). Within the tile, fragments are
//     register double-buffered: phase k's 8 MFMAs overlap phase k+1's 6
//     ds_read_b128 in the SAME wave (compiler emits partial lgkmcnt(6)).
//     All 4 phases of a tile read the same 2 ring slots -> no mid barriers.
//   - counted s_waitcnt vmcnt(4) once per K-tile, never 0 in steady state:
//     chunk j (2 loads) issued during phase (j-6); at tile-T boundary,
//     issued <= chunk 4T+9, tile T+1 needs <= 4T+7 done -> vmcnt(4).
//   - ring safety with 1 barrier/tile: stage() during tile T writes slots
//     (2T+3)%5, (2T+4)%5 == slots last READ during tile T-1; those reads are
//     pinned complete by lgkmcnt(0) before the T-1 -> T barrier.
//   - s_setprio(1) around each MFMA cluster.
// XOR source-chunk swizzle: LDS (row, slot) holds global chunk
// (row, slot ^ (row&7)); fragment reads XOR back -> conflict-free
// ds_read_b128 at 128 B row stride.
#define BM 256
#define BN 256
#define BK 64
#define NT (KDIM / BK)          // 32 K-tiles
#define SLOT_SH (128 * 64)      // shorts per half-tile slot (16 KB)

__device__ __forceinline__ void async_ld16(const unsigned short* g, unsigned short* l) {
    __builtin_amdgcn_global_load_lds(
        (const __attribute__((address_space(1))) void*)g,
        (__attribute__((address_space(3))) void*)l,
        16, 0, 0);
}

__global__ __launch_bounds__(512, 2)
void gemm_pipe(const unsigned short* __restrict__ A,   // M x K bf16
               const unsigned short* __restrict__ Bt,  // N x K bf16 (= W^T)
               float* __restrict__ C) {                // M x N fp32
    __shared__ unsigned short lds[10 * SLOT_SH];   // 160 KB exactly (5 A + 5 B)
    unsigned short* const Abase = lds;
    unsigned short* const Bbase = lds + 5 * SLOT_SH;

    const int tid  = threadIdx.x;
    const int wave = tid >> 6;
    const int lane = tid & 63;
    const int l32  = lane & 31;
    const int kh8  = (lane >> 5) << 3;   // k sub-offset within 16-slice (shorts)
    const int rx8  = (l32 & 7) << 3;     // row&7 XOR term (shorts)
    const int wr   = wave >> 2;          // 0/1: M half of block tile
    const int wc   = wave & 3;           // 0..3: N quarter of block tile
    const int hB   = wc >> 1;            // which B half-tile this wave reads
    const int brow = (wc & 1) * 64;      // row base within B half-tile

    // XCD-aware swizzle: 256 blocks, 8 XCDs, 32 contiguous per XCD (256%8==0).
    const int bid = blockIdx.x;
    const int swz = (bid & 7) * 32 + (bid >> 3);
    const int m0 = (swz >> 3) * BM;      // 32 M-blocks
    const int n0 = (swz & 7) * BN;       // 8  N-blocks

    // Staging: half-tile = 128 rows x 64 k = 1024 16B-chunks; 512 threads x 2.
    // Global k pre-swizzled so linear global_load_lds dest = swizzled layout.
    const int r0 = tid >> 3, s0 = tid & 7;
    const int xo = (s0 ^ (r0 & 7)) << 3;
    const unsigned short* const gA = A  + (size_t)(m0 + r0) * KDIM + xo;
    const unsigned short* const gB = Bt + (size_t)(n0 + r0) * KDIM + xo;

    // chunk j: tile t=j>>2; j&1 -> A/B; (j>>1)&1 -> half. slot=(2t+h)%5.
    auto stage = [&](int j) {
        const int t   = j >> 2;
        const int isB = j & 1;
        const int h   = (j >> 1) & 1;
        const int slot = (2 * t + h) % 5;
        const unsigned short* g = (isB ? gB : gA)
            + (size_t)h * 128 * KDIM + (size_t)t * BK;
        unsigned short* l = (isB ? Bbase : Abase) + slot * SLOT_SH + tid * 8;
        async_ld16(g, l);
        async_ld16(g + (size_t)64 * KDIM, l + 512 * 8);
    };

    f32x16 acc[4][2];
    #pragma unroll
    for (int i = 0; i < 4; ++i)
        #pragma unroll
        for (int j2 = 0; j2 < 2; ++j2) {
            f32x16 z = {0.f,0.f,0.f,0.f,0.f,0.f,0.f,0.f,
                        0.f,0.f,0.f,0.f,0.f,0.f,0.f,0.f};
            acc[i][j2] = z;
        }

    // Prologue: tile0 (chunks 0-3) + tile1 first half (chunks 4,5).
    #pragma unroll
    for (int j = 0; j < 6; ++j) stage(j);
    asm volatile("s_waitcnt vmcnt(4)" ::: "memory");
    asm volatile("s_barrier" ::: "memory");

    for (int T = 0; T < NT; ++T) {
        const unsigned short* const As_ = Abase + ((2 * T + wr) % 5) * SLOT_SH;
        const unsigned short* const Bs_ = Bbase + ((2 * T + hB) % 5) * SLOT_SH;

        bf16x8 af[2][4], bf[2][2];   // register double-buffered fragments
        {   // phase-0 fragment reads
            const int kc = kh8 ^ rx8;
            #pragma unroll
            for (int i = 0; i < 4; ++i)
                af[0][i] = *(const bf16x8*)(As_ + (i * 32 + l32) * 64 + kc);
            #pragma unroll
            for (int j2 = 0; j2 < 2; ++j2)
                bf[0][j2] = *(const bf16x8*)(Bs_ + (brow + j2 * 32 + l32) * 64 + kc);
        }
        #pragma unroll
        for (int ks = 0; ks < 4; ++ks) {
            const int cur = ks & 1, nxt = cur ^ 1;   // static after unroll
            if (ks < 3) {   // prefetch next phase's fragments (same slots)
                const int kc = ((ks + 1) * 16 + kh8) ^ rx8;
                #pragma unroll
                for (int i = 0; i < 4; ++i)
                    af[nxt][i] = *(const bf16x8*)(As_ + (i * 32 + l32) * 64 + kc);
                #pragma unroll
                for (int j2 = 0; j2 < 2; ++j2)
                    bf[nxt][j2] = *(const bf16x8*)(Bs_ + (brow + j2 * 32 + l32) * 64 + kc);
            }
            {   // stage one half-tile 1.5 tiles ahead (2 global_load_lds)
                const int j = 4 * T + ks + 6;
                if (j < 4 * NT) stage(j);
            }
            __builtin_amdgcn_s_setprio(1);
            #pragma unroll
            for (int i = 0; i < 4; ++i)
                #pragma unroll
                for (int j2 = 0; j2 < 2; ++j2)
                    acc[i][j2] = __builtin_amdgcn_mfma_f32_32x32x16_bf16(
                        af[cur][i], bf[cur][j2], acc[i][j2], 0, 0, 0);
            __builtin_amdgcn_s_setprio(0);
        }
        // Pin all tile-T ds_reads complete (ring slots recycled after barrier),
        // then counted vmcnt so 2 half-tile prefetches stay in flight.
        asm volatile("s_waitcnt lgkmcnt(0)" ::: "memory");
        if (T < NT - 2)       asm volatile("s_waitcnt vmcnt(4)" ::: "memory");
        else if (T == NT - 2) asm volatile("s_waitcnt vmcnt(0)" ::: "memory");
        asm volatile("s_barrier" ::: "memory");
    }

    // Epilogue: C/D layout (m74/m101): col=lane&31, row=(r&3)+8*(r>>2)+4*(lane>>5)
    const int kh = kh8 >> 3;
    #pragma unroll
    for (int i = 0; i < 4; ++i)
        #pragma unroll
        for (int j2 = 0; j2 < 2; ++j2)
            #pragma unroll
            for (int r = 0; r < 16; ++r) {
                int row = (r & 3) + 8 * (r >> 2) + 4 * kh;
                int m = m0 + wr * 128 + i * 32 + row;
                int col = n0 + wc * 64 + j2 * 32 + l32;
                float v = acc[i][j2][r];
                C[(size_t)m * NDIM + col] = (v > 0.f) ? v : (__expf(v) - 1.f);
            }
}

extern "C" void kernel_launch(void* const* d_in, const int* in_sizes, int n_in,
                              void* d_out, int out_size, void* d_ws, size_t ws_size,
                              hipStream_t stream) {
    const float* input = (const float*)d_in[0];
    // d_in[1] = adj : numerically unused (attention == I exactly)
    const float* W     = (const float*)d_in[2];
    // d_in[3] = a   : numerically unused
    float* out = (float*)d_out;

    // Workspace: A_bf16 (33.5 MB) then Wt_bf16 (8.4 MB)
    unsigned short* Abf = (unsigned short*)d_ws;
    unsigned short* Wt  = Abf + (size_t)NROW * KDIM;

    prep_kernel<<<CVT_BLOCKS + TRN_BLOCKS, 256, 0, stream>>>(input, Abf, W, Wt);
    gemm_pipe<<<dim3((NROW / BM) * (NDIM / BN)), 512, 0, stream>>>(Abf, Wt, out);
}